// Round 5
// baseline (387.161 us; speedup 1.0000x reference)
//
#include <hip/hip_runtime.h>

// LayoutLMv2 self-attention, MI355X.  B=8 N=1024 H=16 D=64.
// Prep (fp32->bf16 converts + mask->u64 bitmasks) in ONE dispatch; bf16 MFMA
// QKV GEMM (round-3 proven 2-barrier single-buffer form, 89us); flash
// attention: 1 q-strip/wave, MAX-FREE log2-domain softmax, rel+rel2 bias
// COMBINED IN-KERNEL (f32 loads, folded into MFMA C-operand — no separate
// combine pass, no Bb workspace), ZERO LDS round-trip for P (permuted-key
// S-MFMA output IS the O-MFMA B-fragment), packed-bitmask masking.

typedef __bf16 bf16;
typedef __bf16 bf16x8 __attribute__((ext_vector_type(8)));
typedef __bf16 bf16x4 __attribute__((ext_vector_type(4)));
typedef float floatx4 __attribute__((ext_vector_type(4)));

#define MFMA16(a, b, c) __builtin_amdgcn_mfma_f32_16x16x32_bf16((a), (b), (c), 0, 0, 0)

#define LOG2E 1.4426950408889634f

// K-tile LDS chunk swizzle for flash: g bits = (b0^b3, b1^b4, b2^b3) of the
// 6-bit key; spreads the PERMUTED S-MFMA fragment reads over all 8 16B groups.
#define GK(key) ((((key) ^ ((key) >> 3)) & 3) | (((((key) >> 2) ^ ((key) >> 3)) & 1) << 2))

__device__ __forceinline__ void gld16(const bf16* g, bf16* l) {
    __builtin_amdgcn_global_load_lds(
        (const __attribute__((address_space(1))) unsigned int*)g,
        (__attribute__((address_space(3))) unsigned int*)l, 16, 0, 0);
}

// ---------------- fused prep kernel ----------------
// blocks [0,8192): cvt hidden_states f32->bf16
// blocks [8192,11264): cvt qkv_w f32->bf16
// blocks [11264,11296): mask -> packed u64 keep-bitmasks
__global__ __launch_bounds__(256) void prep_kernel(
    const float* __restrict__ hs, const float* __restrict__ qkvw,
    const int* __restrict__ msk,
    bf16* __restrict__ Xb, bf16* __restrict__ Wb,
    unsigned long long* __restrict__ OM) {
    int bid = blockIdx.x, t = threadIdx.x;
    if (bid < 8192) {
        int i = bid * 256 + t;
        float4 v = ((const float4*)hs)[i];
        bf16x4 o;
        o.x = (bf16)v.x; o.y = (bf16)v.y; o.z = (bf16)v.z; o.w = (bf16)v.w;
        ((bf16x4*)Xb)[i] = o;
    } else if (bid < 11264) {
        int i = (bid - 8192) * 256 + t;
        float4 v = ((const float4*)qkvw)[i];
        bf16x4 o;
        o.x = (bf16)v.x; o.y = (bf16)v.y; o.z = (bf16)v.z; o.w = (bf16)v.w;
        ((bf16x4*)Wb)[i] = o;
    } else {
        int tid = (bid - 11264) * 256 + t;
        int gw = tid >> 6, lane = tid & 63;  // gw = b*16 + tile, 0..127
        bool keep = (msk[gw * 64 + lane] == 0);
        unsigned long long bal = __ballot(keep);
        if (lane == 0) OM[gw] = bal;
    }
}

// ---------------- QKV GEMM ----------------
// Round-3 proven form: 128x128 tile, BK=32, single-buffered LDS (16KB),
// 2 barriers per K-step. (Round-4 dbuf experiment: neutral-to-negative.)
__global__ __launch_bounds__(256) void qkv_gemm(
    const bf16* __restrict__ X, const bf16* __restrict__ W,
    const float* __restrict__ qbias, const float* __restrict__ vbias,
    bf16* __restrict__ qbuf, bf16* __restrict__ kbuf, bf16* __restrict__ vbuf) {
    __shared__ __align__(16) bf16 Al[128 * 32];
    __shared__ __align__(16) bf16 Bl[128 * 32];

    int tid = threadIdx.x, lane = tid & 63, w = tid >> 6;
    int quad = lane >> 4, lcol = lane & 15;
    int bx = blockIdx.x;
    int by = blockIdx.y;
    int wr = w >> 1, wc = w & 1;

    floatx4 z4 = {0.f, 0.f, 0.f, 0.f};
    floatx4 acc[4][4];
    for (int i = 0; i < 4; ++i)
        for (int j = 0; j < 4; ++j) acc[i][j] = z4;

    const bf16* Ag = X + (size_t)by * 128 * 1024;
    const bf16* Bg = W + (size_t)bx * 128 * 1024;

    for (int kt = 0; kt < 32; ++kt) {
        int k0 = kt * 32;
        __syncthreads();
        for (int j = 0; j < 2; ++j) {
            int c = (w * 2 + j) * 64 + lane;
            int row = c >> 2;
            int dc = (c & 3) ^ (row & 3);
            gld16(Ag + (size_t)row * 1024 + k0 + dc * 8, &Al[(w * 2 + j) * 64 * 8]);
        }
        for (int j = 0; j < 2; ++j) {
            int c = (w * 2 + j) * 64 + lane;
            int row = c >> 2;
            int dc = (c & 3) ^ (row & 3);
            gld16(Bg + (size_t)row * 1024 + k0 + dc * 8, &Bl[(w * 2 + j) * 64 * 8]);
        }
        __syncthreads();

        bf16x8 af[4], bfr[4];
        for (int i = 0; i < 4; ++i) {
            int r = wr * 64 + i * 16 + lcol;
            af[i] = *(const bf16x8*)&Al[r * 32 + ((quad ^ (r & 3)) * 8)];
        }
        for (int j = 0; j < 4; ++j) {
            int r = wc * 64 + j * 16 + lcol;
            bfr[j] = *(const bf16x8*)&Bl[r * 32 + ((quad ^ (r & 3)) * 8)];
        }
        for (int i = 0; i < 4; ++i)
            for (int j = 0; j < 4; ++j) acc[i][j] = MFMA16(af[i], bfr[j], acc[i][j]);
    }

    int col0 = bx * 128 + wc * 64;
    int row0 = by * 128 + wr * 64;
    int seg = col0 >> 10;

    for (int i = 0; i < 4; ++i) {
        int m0 = row0 + i * 16 + quad * 4;
        int bb = m0 >> 10, n0 = m0 & 1023;
        for (int j = 0; j < 4; ++j) {
            int o = col0 + j * 16 + lcol;
            if (seg == 0) {
                int hh = o >> 6, d = o & 63;
                float qb = qbias[o];
                for (int r = 0; r < 4; ++r) {
                    // q scale 1/8 with log2e folded (softmax in log2 domain)
                    float v = (acc[i][j][r] + qb) * (0.125f * LOG2E);
                    qbuf[((size_t)((bb * 16 + hh) * 1024 + n0 + r)) * 64 + d] = (bf16)v;
                }
            } else if (seg == 1) {
                int o2 = o - 1024;
                int hh = o2 >> 6, d = o2 & 63;
                for (int r = 0; r < 4; ++r) {
                    kbuf[((size_t)((bb * 16 + hh) * 1024 + n0 + r)) * 64 + d] = (bf16)acc[i][j][r];
                }
            } else {
                int o2 = o - 2048;
                int hh = o2 >> 6, d = o2 & 63;
                float vbv = vbias[o2];
                bf16x4 pk;
                pk.x = (bf16)(acc[i][j][0] + vbv);
                pk.y = (bf16)(acc[i][j][1] + vbv);
                pk.z = (bf16)(acc[i][j][2] + vbv);
                pk.w = (bf16)(acc[i][j][3] + vbv);
                *(bf16x4*)&vbuf[((size_t)((bb * 16 + hh) * 64 + d)) * 1024 + n0] = pk;
            }
        }
    }
}

// ---------------- flash attention ----------------
// Block = (b, h, 64 q rows), 4 waves; wave owns ONE 16-row strip.
// S^T = MFMA(A=K permuted rows, B=Q, C=bias). The key permutation
//   key(j, m) = 32*(j>>1) + 8*(m>>2) + 4*(j&1) + (m&3)
// makes the C-layout output (lane quad, reg r) hold keys 8*quad+e directly,
// so (p[0][*], p[1][*]) packs straight into the O-MFMA B-fragment: no P LDS
// round-trip, no cross-lane ops. Bias = (rel+rel2)*log2e computed IN-KERNEL
// from f32 (combine pass eliminated); packed into the same bf16x4 prefetch
// registers so the register profile is unchanged vs the verified round-3
// kernel. Mask via packed u64 bitmask select. O^T = MFMA(A=Vt, B=P).
__global__ __launch_bounds__(256, 4) void flash_attn(
    const bf16* __restrict__ qbuf, const bf16* __restrict__ kbuf,
    const bf16* __restrict__ vbuf, const float* __restrict__ rel,
    const float* __restrict__ rel2,
    const unsigned long long* __restrict__ om64, float* __restrict__ out) {
    __shared__ __align__(16) bf16 Kl[2][64 * 64];
    __shared__ __align__(16) bf16 Vl[2][64 * 64];

    int tid = threadIdx.x, lane = tid & 63, w = tid >> 6;
    int quad = lane >> 4, lcol = lane & 15;
    int bx = blockIdx.x;
    // XCD-aware decode (XCD = bx % 8): each XCD owns 2 heads x 16 q-tiles;
    // the 8 batch-blocks of a (h,q4) run back-to-back (bias strip x8 L2
    // reuse); K/V of (b,h) reused across the 16 q4 of that h (~2MB set).
    int xcd = bx & 7, slot = bx >> 3;
    int pair = xcd * 32 + (slot >> 3);  // 0..255
    int b = slot & 7;
    int h = pair >> 4, q4 = pair & 15;

    const bf16* kb = kbuf + ((size_t)((b * 16 + h) * 1024)) * 64;
    const bf16* vb = vbuf + ((size_t)((b * 16 + h) * 64)) * 1024;  // [d][n]
    const unsigned long long* mp = om64 + b * 16;

    int qrow = q4 * 64 + w * 16;
    const bf16* qp = qbuf + ((size_t)((b * 16 + h) * 1024 + qrow + lcol)) * 64;
    bf16x8 qf0 = *(const bf16x8*)(qp + quad * 8);
    bf16x8 qf1 = *(const bf16x8*)(qp + 32 + quad * 8);
    const float* b0 = rel + (size_t)h * 1024 * 1024 + (size_t)(qrow + lcol) * 1024;
    const float* b1 = rel2 + (size_t)h * 1024 * 1024 + (size_t)(qrow + lcol) * 1024;

    floatx4 z4 = {0.f, 0.f, 0.f, 0.f};
    floatx4 oacc[4] = {z4, z4, z4, z4};
    float lrun = 0.f;

    // stage tile 0 into buffer 0
#pragma unroll
    for (int j = 0; j < 2; ++j) {
        int c = (w * 2 + j) * 64 + lane;
        int key = c >> 3;
        int dc = (c & 7) ^ GK(key);
        gld16(kb + (size_t)key * 64 + dc * 8, &Kl[0][(w * 2 + j) * 512]);
    }
#pragma unroll
    for (int j = 0; j < 2; ++j) {
        int c = (w * 2 + j) * 64 + lane;
        int d = c >> 3;
        int kc = (c & 7) ^ (d & 7);
        gld16(vb + (size_t)d * 1024 + kc * 8, &Vl[0][(w * 2 + j) * 512]);
    }

    // prefetch bias = (rel+rel2)*log2e (f32 loads, packed to bf16x4 in the
    // PERMUTED key order matching the S-MFMA C layout) + mask
    bf16x4 bf_[4];
#pragma unroll
    for (int j = 0; j < 4; ++j) {
        int kboff = ((j >> 1) << 5) + (quad << 3) + ((j & 1) << 2);
        floatx4 ra = *(const floatx4*)(b0 + kboff);
        floatx4 rb = *(const floatx4*)(b1 + kboff);
        bf_[j].x = (bf16)((ra[0] + rb[0]) * LOG2E);
        bf_[j].y = (bf16)((ra[1] + rb[1]) * LOG2E);
        bf_[j].z = (bf16)((ra[2] + rb[2]) * LOG2E);
        bf_[j].w = (bf16)((ra[3] + rb[3]) * LOG2E);
    }
    unsigned long long mcur = mp[0];

    for (int kt = 0; kt < 16; ++kt) {
        int k0 = kt * 64;
        int cur = kt & 1, nxt = cur ^ 1;
        __syncthreads();  // buf[cur] staged; buf[nxt] free

        // stage tile kt+1 into buf[nxt]
        if (kt < 15) {
            int k1 = k0 + 64;
#pragma unroll
            for (int j = 0; j < 2; ++j) {
                int c = (w * 2 + j) * 64 + lane;
                int key = c >> 3;
                int dc = (c & 7) ^ GK(key);
                gld16(kb + (size_t)(k1 + key) * 64 + dc * 8, &Kl[nxt][(w * 2 + j) * 512]);
            }
#pragma unroll
            for (int j = 0; j < 2; ++j) {
                int c = (w * 2 + j) * 64 + lane;
                int d = c >> 3;
                int kc = (c & 7) ^ (d & 7);
                gld16(vb + (size_t)d * 1024 + k1 + kc * 8, &Vl[nxt][(w * 2 + j) * 512]);
            }
        }
        int kp = (kt < 15) ? k0 + 64 : 0;
        bf16x4 bn[4];
#pragma unroll
        for (int j = 0; j < 4; ++j) {
            int kboff = ((j >> 1) << 5) + (quad << 3) + ((j & 1) << 2);
            floatx4 ra = *(const floatx4*)(b0 + kp + kboff);
            floatx4 rb = *(const floatx4*)(b1 + kp + kboff);
            bn[j].x = (bf16)((ra[0] + rb[0]) * LOG2E);
            bn[j].y = (bf16)((ra[1] + rb[1]) * LOG2E);
            bn[j].z = (bf16)((ra[2] + rb[2]) * LOG2E);
            bn[j].w = (bf16)((ra[3] + rb[3]) * LOG2E);
        }
        unsigned long long mn = mp[(kt < 15) ? kt + 1 : 0];

        // S^T + bias = MFMA(A=K permuted, B=Q, C=bias)
        floatx4 sacc[4];
#pragma unroll
        for (int j = 0; j < 4; ++j) {
            int key = ((j >> 1) << 5) + ((lcol >> 2) << 3) + ((j & 1) << 2) + (lcol & 3);
            int gk = GK(key);
            bf16x8 kf0 = *(const bf16x8*)&Kl[cur][key * 64 + ((quad ^ gk) * 8)];
            bf16x8 kf1 = *(const bf16x8*)&Kl[cur][key * 64 + (((4 + quad) ^ gk) * 8)];
            floatx4 binit;
            binit[0] = (float)bf_[j][0]; binit[1] = (float)bf_[j][1];
            binit[2] = (float)bf_[j][2]; binit[3] = (float)bf_[j][3];
            sacc[j] = MFMA16(kf0, qf0, binit);
            sacc[j] = MFMA16(kf1, qf1, sacc[j]);
        }

        // mask-select + p = exp2(sv); per-lane lrun partials (no shuffles).
        // this lane's 16 keys are bits {8q..8q+7, 32+8q..32+8q+7} of mcur,
        // packed so element (j,r) is bit j*4+r of mbits.
        unsigned int mbits = ((unsigned int)(mcur >> (8 * quad)) & 0xffu) |
                             (((unsigned int)(mcur >> (32 + 8 * quad)) & 0xffu) << 8);
        float p[4][4];
        float psum = 0.f;
#pragma unroll
        for (int j = 0; j < 4; ++j)
#pragma unroll
            for (int r = 0; r < 4; ++r) {
                float sv = ((mbits >> (j * 4 + r)) & 1u) ? sacc[j][r] : 0.f;
                p[j][r] = __builtin_amdgcn_exp2f(sv);
                psum += p[j][r];
            }
        lrun += psum;

        // pack P straight into B-operand fragments (keys already lane-local):
        // pf0 = keys 8q+0..7 = (p[0][0..3], p[1][0..3]); pf1 = +32.
        bf16x8 pf0, pf1;
        pf0[0] = (bf16)p[0][0]; pf0[1] = (bf16)p[0][1];
        pf0[2] = (bf16)p[0][2]; pf0[3] = (bf16)p[0][3];
        pf0[4] = (bf16)p[1][0]; pf0[5] = (bf16)p[1][1];
        pf0[6] = (bf16)p[1][2]; pf0[7] = (bf16)p[1][3];
        pf1[0] = (bf16)p[2][0]; pf1[1] = (bf16)p[2][1];
        pf1[2] = (bf16)p[2][2]; pf1[3] = (bf16)p[2][3];
        pf1[4] = (bf16)p[3][0]; pf1[5] = (bf16)p[3][1];
        pf1[6] = (bf16)p[3][2]; pf1[7] = (bf16)p[3][3];

        // O^T += Vt P^T
#pragma unroll
        for (int jd = 0; jd < 4; ++jd) {
            int dd = jd * 16 + lcol;
            bf16x8 vf0 = *(const bf16x8*)&Vl[cur][dd * 64 + ((quad ^ (dd & 7)) * 8)];
            bf16x8 vf1 = *(const bf16x8*)&Vl[cur][dd * 64 + (((4 + quad) ^ (dd & 7)) * 8)];
            oacc[jd] = MFMA16(vf0, pf0, oacc[jd]);
            oacc[jd] = MFMA16(vf1, pf1, oacc[jd]);
        }

        // rotate bias/mask prefetch
#pragma unroll
        for (int j = 0; j < 4; ++j) bf_[j] = bn[j];
        mcur = mn;
    }

    // epilogue: reduce lrun across quads (once), normalize, store
    float l = lrun;
    l += __shfl_xor(l, 16);
    l += __shfl_xor(l, 32);
    float linv = 1.f / l;
#pragma unroll
    for (int jd = 0; jd < 4; ++jd) {
        float4 st;
        st.x = oacc[jd][0] * linv;
        st.y = oacc[jd][1] * linv;
        st.z = oacc[jd][2] * linv;
        st.w = oacc[jd][3] * linv;
        *(float4*)&out[((size_t)(b * 1024 + qrow + lcol)) * 1024 + h * 64 + jd * 16 + quad * 4] = st;
    }
}

// ---------------- launch ----------------
extern "C" void kernel_launch(void* const* d_in, const int* in_sizes, int n_in,
                              void* d_out, int out_size, void* d_ws, size_t ws_size,
                              hipStream_t stream) {
    const float* hs   = (const float*)d_in[0];
    const float* qkvw = (const float*)d_in[1];
    const float* qb   = (const float*)d_in[2];
    const float* vbi  = (const float*)d_in[3];
    const float* rel  = (const float*)d_in[4];
    const float* rel2 = (const float*)d_in[5];
    const int*   msk  = (const int*)d_in[6];
    float* out = (float*)d_out;

    char* w = (char*)d_ws;
    bf16* Xb = (bf16*)w;  w += (size_t)8388608 * 2;
    bf16* Wb = (bf16*)w;  w += (size_t)3145728 * 2;
    bf16* Qb = (bf16*)w;  w += (size_t)8388608 * 2;
    bf16* Kb = (bf16*)w;  w += (size_t)8388608 * 2;
    bf16* Vb = (bf16*)w;  w += (size_t)8388608 * 2;
    unsigned long long* OM = (unsigned long long*)w; w += (size_t)128 * 8;

    prep_kernel<<<11296, 256, 0, stream>>>(hs, qkvw, msk, Xb, Wb, OM);
    qkv_gemm<<<dim3(24, 64), 256, 0, stream>>>(Xb, Wb, qb, vbi, Qb, Kb, Vb);
    flash_attn<<<2048, 256, 0, stream>>>(Qb, Kb, Vb, rel, rel2, OM, out);
}

// Round 7
// 341.053 us; speedup vs baseline: 1.1352x; 1.1352x over previous
//
#include <hip/hip_runtime.h>

// LayoutLMv2 self-attention, MI355X.  B=8 N=1024 H=16 D=64.
// Fused prep (fp32->bf16 converts, bias combine w/ log2e fold, mask->u64
// bitmasks) in ONE dispatch; bf16 MFMA QKV GEMM (128x128 tile, BK=64: half
// the barrier drains of BK=32, staging/fragment swizzle transplanted from
// flash's zero-conflict 64-wide K/V pattern); flash attention: 1 q-strip/wave,
// MAX-FREE log2-domain softmax, precombined bf16 bias folded into MFMA
// C-operand (round-5 lesson: in-kernel f32 combine is latency-bound),
// ZERO LDS round-trip for P (permuted-key S-MFMA output IS the O-MFMA
// B-fragment), packed-bitmask masking.

typedef __bf16 bf16;
typedef __bf16 bf16x8 __attribute__((ext_vector_type(8)));
typedef __bf16 bf16x4 __attribute__((ext_vector_type(4)));
typedef float floatx4 __attribute__((ext_vector_type(4)));

#define MFMA16(a, b, c) __builtin_amdgcn_mfma_f32_16x16x32_bf16((a), (b), (c), 0, 0, 0)

#define LOG2E 1.4426950408889634f

// K-tile LDS chunk swizzle for flash: g bits = (b0^b3, b1^b4, b2^b3) of the
// 6-bit key; spreads the PERMUTED S-MFMA fragment reads over all 8 16B groups.
#define GK(key) ((((key) ^ ((key) >> 3)) & 3) | (((((key) >> 2) ^ ((key) >> 3)) & 1) << 2))

__device__ __forceinline__ void gld16(const bf16* g, bf16* l) {
    __builtin_amdgcn_global_load_lds(
        (const __attribute__((address_space(1))) unsigned int*)g,
        (__attribute__((address_space(3))) unsigned int*)l, 16, 0, 0);
}

// ---------------- fused prep kernel ----------------
// blocks [0,16384): bias combine (rel+rel2)*log2e -> bf16
// blocks [16384,24576): cvt hidden_states f32->bf16
// blocks [24576,27648): cvt qkv_w f32->bf16
// blocks [27648,27680): mask -> packed u64 keep-bitmasks
__global__ __launch_bounds__(256) void prep_kernel(
    const float* __restrict__ hs, const float* __restrict__ qkvw,
    const float* __restrict__ rel, const float* __restrict__ rel2,
    const int* __restrict__ msk,
    bf16* __restrict__ Xb, bf16* __restrict__ Wb, bf16* __restrict__ Bb,
    unsigned long long* __restrict__ OM) {
    int bid = blockIdx.x, t = threadIdx.x;
    if (bid < 16384) {
        int i = bid * 256 + t;
        float4 va = ((const float4*)rel)[i];
        float4 vb = ((const float4*)rel2)[i];
        bf16x4 o;
        o.x = (bf16)((va.x + vb.x) * LOG2E); o.y = (bf16)((va.y + vb.y) * LOG2E);
        o.z = (bf16)((va.z + vb.z) * LOG2E); o.w = (bf16)((va.w + vb.w) * LOG2E);
        ((bf16x4*)Bb)[i] = o;
    } else if (bid < 24576) {
        int i = (bid - 16384) * 256 + t;
        float4 v = ((const float4*)hs)[i];
        bf16x4 o;
        o.x = (bf16)v.x; o.y = (bf16)v.y; o.z = (bf16)v.z; o.w = (bf16)v.w;
        ((bf16x4*)Xb)[i] = o;
    } else if (bid < 27648) {
        int i = (bid - 24576) * 256 + t;
        float4 v = ((const float4*)qkvw)[i];
        bf16x4 o;
        o.x = (bf16)v.x; o.y = (bf16)v.y; o.z = (bf16)v.z; o.w = (bf16)v.w;
        ((bf16x4*)Wb)[i] = o;
    } else {
        int tid = (bid - 27648) * 256 + t;
        int gw = tid >> 6, lane = tid & 63;  // gw = b*16 + tile, 0..127
        bool keep = (msk[gw * 64 + lane] == 0);
        unsigned long long bal = __ballot(keep);
        if (lane == 0) OM[gw] = bal;
    }
}

// ---------------- QKV GEMM ----------------
// 128x128 tile, BK=64, single-buffered LDS (32KB), 2 barriers per K-step but
// only 16 K-steps (half the vmcnt(0) drains of BK=32) and 32 MFMA/step.
// Staging + fragment-read swizzle is the verbatim 64-wide pattern from
// flash's K/V tiles, which measures SQ_LDS_BANK_CONFLICT = 0.
__global__ __launch_bounds__(256) void qkv_gemm(
    const bf16* __restrict__ X, const bf16* __restrict__ W,
    const float* __restrict__ qbias, const float* __restrict__ vbias,
    bf16* __restrict__ qbuf, bf16* __restrict__ kbuf, bf16* __restrict__ vbuf) {
    __shared__ __align__(16) bf16 Al[128 * 64];
    __shared__ __align__(16) bf16 Bl[128 * 64];

    int tid = threadIdx.x, lane = tid & 63, w = tid >> 6;
    int quad = lane >> 4, lcol = lane & 15;
    int bx = blockIdx.x;
    int by = blockIdx.y;
    int wr = w >> 1, wc = w & 1;

    floatx4 z4 = {0.f, 0.f, 0.f, 0.f};
    floatx4 acc[4][4];
    for (int i = 0; i < 4; ++i)
        for (int j = 0; j < 4; ++j) acc[i][j] = z4;

    const bf16* Ag = X + (size_t)by * 128 * 1024;
    const bf16* Bg = W + (size_t)bx * 128 * 1024;

    for (int kt = 0; kt < 16; ++kt) {
        int k0 = kt * 64;
        __syncthreads();
#pragma unroll
        for (int j = 0; j < 4; ++j) {
            int c = (w * 4 + j) * 64 + lane;  // chunk 0..1023
            int row = c >> 3;                 // 0..127
            int dc = (c & 7) ^ (row & 7);
            gld16(Ag + (size_t)row * 1024 + k0 + dc * 8, &Al[(w * 4 + j) * 512]);
        }
#pragma unroll
        for (int j = 0; j < 4; ++j) {
            int c = (w * 4 + j) * 64 + lane;
            int row = c >> 3;
            int dc = (c & 7) ^ (row & 7);
            gld16(Bg + (size_t)row * 1024 + k0 + dc * 8, &Bl[(w * 4 + j) * 512]);
        }
        __syncthreads();

        bf16x8 bfr0[4], bfr1[4];
#pragma unroll
        for (int j = 0; j < 4; ++j) {
            int r = wc * 64 + j * 16 + lcol;
            bfr0[j] = *(const bf16x8*)&Bl[r * 64 + ((quad ^ (r & 7)) * 8)];
            bfr1[j] = *(const bf16x8*)&Bl[r * 64 + (((4 + quad) ^ (r & 7)) * 8)];
        }
#pragma unroll
        for (int i = 0; i < 4; ++i) {
            int r = wr * 64 + i * 16 + lcol;
            bf16x8 a0 = *(const bf16x8*)&Al[r * 64 + ((quad ^ (r & 7)) * 8)];
            bf16x8 a1 = *(const bf16x8*)&Al[r * 64 + (((4 + quad) ^ (r & 7)) * 8)];
#pragma unroll
            for (int j = 0; j < 4; ++j) {
                acc[i][j] = MFMA16(a0, bfr0[j], acc[i][j]);
                acc[i][j] = MFMA16(a1, bfr1[j], acc[i][j]);
            }
        }
    }

    int col0 = bx * 128 + wc * 64;
    int row0 = by * 128 + wr * 64;
    int seg = col0 >> 10;

    for (int i = 0; i < 4; ++i) {
        int m0 = row0 + i * 16 + quad * 4;
        int bb = m0 >> 10, n0 = m0 & 1023;
        for (int j = 0; j < 4; ++j) {
            int o = col0 + j * 16 + lcol;
            if (seg == 0) {
                int hh = o >> 6, d = o & 63;
                float qb = qbias[o];
                for (int r = 0; r < 4; ++r) {
                    // q scale 1/8 with log2e folded (softmax in log2 domain)
                    float v = (acc[i][j][r] + qb) * (0.125f * LOG2E);
                    qbuf[((size_t)((bb * 16 + hh) * 1024 + n0 + r)) * 64 + d] = (bf16)v;
                }
            } else if (seg == 1) {
                int o2 = o - 1024;
                int hh = o2 >> 6, d = o2 & 63;
                for (int r = 0; r < 4; ++r) {
                    kbuf[((size_t)((bb * 16 + hh) * 1024 + n0 + r)) * 64 + d] = (bf16)acc[i][j][r];
                }
            } else {
                int o2 = o - 2048;
                int hh = o2 >> 6, d = o2 & 63;
                float vbv = vbias[o2];
                bf16x4 pk;
                pk.x = (bf16)(acc[i][j][0] + vbv);
                pk.y = (bf16)(acc[i][j][1] + vbv);
                pk.z = (bf16)(acc[i][j][2] + vbv);
                pk.w = (bf16)(acc[i][j][3] + vbv);
                *(bf16x4*)&vbuf[((size_t)((bb * 16 + hh) * 64 + d)) * 1024 + n0] = pk;
            }
        }
    }
}

// ---------------- flash attention ----------------
// Block = (b, h, 64 q rows), 4 waves; wave owns ONE 16-row strip.
// S^T = MFMA(A=K permuted rows, B=Q, C=bias). The key permutation
//   key(j, m) = 32*(j>>1) + 8*(m>>2) + 4*(j&1) + (m&3)
// makes the C-layout output (lane quad, reg r) hold keys 8*quad+e directly,
// so (p[0][*], p[1][*]) packs straight into the O-MFMA B-fragment: no P LDS
// round-trip, no cross-lane ops. Mask via packed u64 bitmask select
// (masked key -> sv=0 -> p=1.0 == exp(1e-8) within bf16). O^T = MFMA(A=Vt,B=P).
__global__ __launch_bounds__(256, 4) void flash_attn(
    const bf16* __restrict__ qbuf, const bf16* __restrict__ kbuf,
    const bf16* __restrict__ vbuf, const bf16* __restrict__ bias,
    const unsigned long long* __restrict__ om64, float* __restrict__ out) {
    __shared__ __align__(16) bf16 Kl[2][64 * 64];
    __shared__ __align__(16) bf16 Vl[2][64 * 64];

    int tid = threadIdx.x, lane = tid & 63, w = tid >> 6;
    int quad = lane >> 4, lcol = lane & 15;
    int bx = blockIdx.x;
    // XCD-aware decode (XCD = bx % 8): each XCD owns 2 heads x 16 q-tiles;
    // the 8 batch-blocks of a (h,q4) run back-to-back (bias tile 128KB x8
    // L2 reuse); K/V of (b,h) reused across the 16 q4 of that h (~2MB set).
    int xcd = bx & 7, slot = bx >> 3;
    int pair = xcd * 32 + (slot >> 3);  // 0..255
    int b = slot & 7;
    int h = pair >> 4, q4 = pair & 15;

    const bf16* kb = kbuf + ((size_t)((b * 16 + h) * 1024)) * 64;
    const bf16* vb = vbuf + ((size_t)((b * 16 + h) * 64)) * 1024;  // [d][n]
    const unsigned long long* mp = om64 + b * 16;

    int qrow = q4 * 64 + w * 16;
    const bf16* qp = qbuf + ((size_t)((b * 16 + h) * 1024 + qrow + lcol)) * 64;
    bf16x8 qf0 = *(const bf16x8*)(qp + quad * 8);
    bf16x8 qf1 = *(const bf16x8*)(qp + 32 + quad * 8);
    const bf16* bb = bias + (size_t)h * 1024 * 1024 + (size_t)(qrow + lcol) * 1024;

    floatx4 z4 = {0.f, 0.f, 0.f, 0.f};
    floatx4 oacc[4] = {z4, z4, z4, z4};
    float lrun = 0.f;

    // stage tile 0 into buffer 0
#pragma unroll
    for (int j = 0; j < 2; ++j) {
        int c = (w * 2 + j) * 64 + lane;
        int key = c >> 3;
        int dc = (c & 7) ^ GK(key);
        gld16(kb + (size_t)key * 64 + dc * 8, &Kl[0][(w * 2 + j) * 512]);
    }
#pragma unroll
    for (int j = 0; j < 2; ++j) {
        int c = (w * 2 + j) * 64 + lane;
        int d = c >> 3;
        int kc = (c & 7) ^ (d & 7);
        gld16(vb + (size_t)d * 1024 + kc * 8, &Vl[0][(w * 2 + j) * 512]);
    }

    // prefetch bias (bf16, PERMUTED key order matching S-MFMA C layout) + mask
    bf16x4 bf_[4];
#pragma unroll
    for (int j = 0; j < 4; ++j) {
        int kboff = ((j >> 1) << 5) + (quad << 3) + ((j & 1) << 2);
        bf_[j] = *(const bf16x4*)(bb + kboff);
    }
    unsigned long long mcur = mp[0];

    for (int kt = 0; kt < 16; ++kt) {
        int k0 = kt * 64;
        int cur = kt & 1, nxt = cur ^ 1;
        __syncthreads();  // buf[cur] staged; buf[nxt] free

        // stage tile kt+1 into buf[nxt]
        if (kt < 15) {
            int k1 = k0 + 64;
#pragma unroll
            for (int j = 0; j < 2; ++j) {
                int c = (w * 2 + j) * 64 + lane;
                int key = c >> 3;
                int dc = (c & 7) ^ GK(key);
                gld16(kb + (size_t)(k1 + key) * 64 + dc * 8, &Kl[nxt][(w * 2 + j) * 512]);
            }
#pragma unroll
            for (int j = 0; j < 2; ++j) {
                int c = (w * 2 + j) * 64 + lane;
                int d = c >> 3;
                int kc = (c & 7) ^ (d & 7);
                gld16(vb + (size_t)d * 1024 + k1 + kc * 8, &Vl[nxt][(w * 2 + j) * 512]);
            }
        }
        int kp = (kt < 15) ? k0 + 64 : 0;
        bf16x4 bn[4];
#pragma unroll
        for (int j = 0; j < 4; ++j) {
            int kboff = ((j >> 1) << 5) + (quad << 3) + ((j & 1) << 2);
            bn[j] = *(const bf16x4*)(bb + kp + kboff);
        }
        unsigned long long mn = mp[(kt < 15) ? kt + 1 : 0];

        // S^T + bias = MFMA(A=K permuted, B=Q, C=bias)
        floatx4 sacc[4];
#pragma unroll
        for (int j = 0; j < 4; ++j) {
            int key = ((j >> 1) << 5) + ((lcol >> 2) << 3) + ((j & 1) << 2) + (lcol & 3);
            int gk = GK(key);
            bf16x8 kf0 = *(const bf16x8*)&Kl[cur][key * 64 + ((quad ^ gk) * 8)];
            bf16x8 kf1 = *(const bf16x8*)&Kl[cur][key * 64 + (((4 + quad) ^ gk) * 8)];
            floatx4 binit;
            binit[0] = (float)bf_[j][0]; binit[1] = (float)bf_[j][1];
            binit[2] = (float)bf_[j][2]; binit[3] = (float)bf_[j][3];
            sacc[j] = MFMA16(kf0, qf0, binit);
            sacc[j] = MFMA16(kf1, qf1, sacc[j]);
        }

        // mask-select + p = exp2(sv); per-lane lrun partials (no shuffles).
        // this lane's 16 keys are bits {8q..8q+7, 32+8q..32+8q+7} of mcur,
        // packed so element (j,r) is bit j*4+r of mbits.
        unsigned int mbits = ((unsigned int)(mcur >> (8 * quad)) & 0xffu) |
                             (((unsigned int)(mcur >> (32 + 8 * quad)) & 0xffu) << 8);
        float p[4][4];
        float psum = 0.f;
#pragma unroll
        for (int j = 0; j < 4; ++j)
#pragma unroll
            for (int r = 0; r < 4; ++r) {
                float sv = ((mbits >> (j * 4 + r)) & 1u) ? sacc[j][r] : 0.f;
                p[j][r] = __builtin_amdgcn_exp2f(sv);
                psum += p[j][r];
            }
        lrun += psum;

        // pack P straight into B-operand fragments (keys already lane-local):
        // pf0 = keys 8q+0..7 = (p[0][0..3], p[1][0..3]); pf1 = +32.
        bf16x8 pf0, pf1;
        pf0[0] = (bf16)p[0][0]; pf0[1] = (bf16)p[0][1];
        pf0[2] = (bf16)p[0][2]; pf0[3] = (bf16)p[0][3];
        pf0[4] = (bf16)p[1][0]; pf0[5] = (bf16)p[1][1];
        pf0[6] = (bf16)p[1][2]; pf0[7] = (bf16)p[1][3];
        pf1[0] = (bf16)p[2][0]; pf1[1] = (bf16)p[2][1];
        pf1[2] = (bf16)p[2][2]; pf1[3] = (bf16)p[2][3];
        pf1[4] = (bf16)p[3][0]; pf1[5] = (bf16)p[3][1];
        pf1[6] = (bf16)p[3][2]; pf1[7] = (bf16)p[3][3];

        // O^T += Vt P^T
#pragma unroll
        for (int jd = 0; jd < 4; ++jd) {
            int dd = jd * 16 + lcol;
            bf16x8 vf0 = *(const bf16x8*)&Vl[cur][dd * 64 + ((quad ^ (dd & 7)) * 8)];
            bf16x8 vf1 = *(const bf16x8*)&Vl[cur][dd * 64 + (((4 + quad) ^ (dd & 7)) * 8)];
            oacc[jd] = MFMA16(vf0, pf0, oacc[jd]);
            oacc[jd] = MFMA16(vf1, pf1, oacc[jd]);
        }

        // rotate bias/mask prefetch
#pragma unroll
        for (int j = 0; j < 4; ++j) bf_[j] = bn[j];
        mcur = mn;
    }

    // epilogue: reduce lrun across quads (once), normalize, store
    float l = lrun;
    l += __shfl_xor(l, 16);
    l += __shfl_xor(l, 32);
    float linv = 1.f / l;
#pragma unroll
    for (int jd = 0; jd < 4; ++jd) {
        float4 st;
        st.x = oacc[jd][0] * linv;
        st.y = oacc[jd][1] * linv;
        st.z = oacc[jd][2] * linv;
        st.w = oacc[jd][3] * linv;
        *(float4*)&out[((size_t)(b * 1024 + qrow + lcol)) * 1024 + h * 64 + jd * 16 + quad * 4] = st;
    }
}

// ---------------- launch ----------------
extern "C" void kernel_launch(void* const* d_in, const int* in_sizes, int n_in,
                              void* d_out, int out_size, void* d_ws, size_t ws_size,
                              hipStream_t stream) {
    const float* hs   = (const float*)d_in[0];
    const float* qkvw = (const float*)d_in[1];
    const float* qb   = (const float*)d_in[2];
    const float* vbi  = (const float*)d_in[3];
    const float* rel  = (const float*)d_in[4];
    const float* rel2 = (const float*)d_in[5];
    const int*   msk  = (const int*)d_in[6];
    float* out = (float*)d_out;

    char* w = (char*)d_ws;
    bf16* Xb = (bf16*)w;  w += (size_t)8388608 * 2;
    bf16* Wb = (bf16*)w;  w += (size_t)3145728 * 2;
    bf16* Bb = (bf16*)w;  w += (size_t)16777216 * 2;
    bf16* Qb = (bf16*)w;  w += (size_t)8388608 * 2;
    bf16* Kb = (bf16*)w;  w += (size_t)8388608 * 2;
    bf16* Vb = (bf16*)w;  w += (size_t)8388608 * 2;
    unsigned long long* OM = (unsigned long long*)w; w += (size_t)128 * 8;

    prep_kernel<<<27680, 256, 0, stream>>>(hs, qkvw, rel, rel2, msk, Xb, Wb, Bb, OM);
    qkv_gemm<<<dim3(24, 64), 256, 0, stream>>>(Xb, Wb, qb, vbi, Qb, Kb, Vb);
    flash_attn<<<2048, 256, 0, stream>>>(Qb, Kb, Vb, Bb, OM, out);
}

// Round 8
// 337.171 us; speedup vs baseline: 1.1483x; 1.0115x over previous
//
#include <hip/hip_runtime.h>

// LayoutLMv2 self-attention, MI355X.  B=8 N=1024 H=16 D=64.
// Fused prep (fp32->bf16 converts, bias combine w/ log2e fold, mask->u64
// bitmasks) in ONE dispatch; bf16 MFMA QKV GEMM (128x128 tile, BK=64, 16
// K-steps, zero-conflict 64-wide swizzle, launch_bounds(256,4) VGPR cap);
// flash attention: 1 q-strip/wave, MAX-FREE log2-domain softmax, precombined
// bf16 bias folded into MFMA C-operand, ZERO LDS round-trip for P
// (permuted-key S-MFMA output IS the O-MFMA B-fragment), packed-bitmask
// masking, tree-reduced psum, launch_bounds(256,5): 5 blocks/CU = 160KB LDS
// exactly, 20 waves/CU (was 16).

typedef __bf16 bf16;
typedef __bf16 bf16x8 __attribute__((ext_vector_type(8)));
typedef __bf16 bf16x4 __attribute__((ext_vector_type(4)));
typedef float floatx4 __attribute__((ext_vector_type(4)));

#define MFMA16(a, b, c) __builtin_amdgcn_mfma_f32_16x16x32_bf16((a), (b), (c), 0, 0, 0)

#define LOG2E 1.4426950408889634f

// K-tile LDS chunk swizzle for flash: g bits = (b0^b3, b1^b4, b2^b3) of the
// 6-bit key; spreads the PERMUTED S-MFMA fragment reads over all 8 16B groups.
#define GK(key) ((((key) ^ ((key) >> 3)) & 3) | (((((key) >> 2) ^ ((key) >> 3)) & 1) << 2))

__device__ __forceinline__ void gld16(const bf16* g, bf16* l) {
    __builtin_amdgcn_global_load_lds(
        (const __attribute__((address_space(1))) unsigned int*)g,
        (__attribute__((address_space(3))) unsigned int*)l, 16, 0, 0);
}

// ---------------- fused prep kernel ----------------
// blocks [0,16384): bias combine (rel+rel2)*log2e -> bf16
// blocks [16384,24576): cvt hidden_states f32->bf16
// blocks [24576,27648): cvt qkv_w f32->bf16
// blocks [27648,27680): mask -> packed u64 keep-bitmasks
__global__ __launch_bounds__(256) void prep_kernel(
    const float* __restrict__ hs, const float* __restrict__ qkvw,
    const float* __restrict__ rel, const float* __restrict__ rel2,
    const int* __restrict__ msk,
    bf16* __restrict__ Xb, bf16* __restrict__ Wb, bf16* __restrict__ Bb,
    unsigned long long* __restrict__ OM) {
    int bid = blockIdx.x, t = threadIdx.x;
    if (bid < 16384) {
        int i = bid * 256 + t;
        float4 va = ((const float4*)rel)[i];
        float4 vb = ((const float4*)rel2)[i];
        bf16x4 o;
        o.x = (bf16)((va.x + vb.x) * LOG2E); o.y = (bf16)((va.y + vb.y) * LOG2E);
        o.z = (bf16)((va.z + vb.z) * LOG2E); o.w = (bf16)((va.w + vb.w) * LOG2E);
        ((bf16x4*)Bb)[i] = o;
    } else if (bid < 24576) {
        int i = (bid - 16384) * 256 + t;
        float4 v = ((const float4*)hs)[i];
        bf16x4 o;
        o.x = (bf16)v.x; o.y = (bf16)v.y; o.z = (bf16)v.z; o.w = (bf16)v.w;
        ((bf16x4*)Xb)[i] = o;
    } else if (bid < 27648) {
        int i = (bid - 24576) * 256 + t;
        float4 v = ((const float4*)qkvw)[i];
        bf16x4 o;
        o.x = (bf16)v.x; o.y = (bf16)v.y; o.z = (bf16)v.z; o.w = (bf16)v.w;
        ((bf16x4*)Wb)[i] = o;
    } else {
        int tid = (bid - 27648) * 256 + t;
        int gw = tid >> 6, lane = tid & 63;  // gw = b*16 + tile, 0..127
        bool keep = (msk[gw * 64 + lane] == 0);
        unsigned long long bal = __ballot(keep);
        if (lane == 0) OM[gw] = bal;
    }
}

// ---------------- QKV GEMM ----------------
// 128x128 tile, BK=64, single-buffered LDS (32KB), 2 barriers per K-step but
// only 16 K-steps and 32 MFMA/step.  64-wide staging/fragment swizzle
// (measured SQ_LDS_BANK_CONFLICT = 0).  launch_bounds(256,4) caps VGPR at 128
// so 4 blocks/CU are guaranteed.
__global__ __launch_bounds__(256, 4) void qkv_gemm(
    const bf16* __restrict__ X, const bf16* __restrict__ W,
    const float* __restrict__ qbias, const float* __restrict__ vbias,
    bf16* __restrict__ qbuf, bf16* __restrict__ kbuf, bf16* __restrict__ vbuf) {
    __shared__ __align__(16) bf16 Al[128 * 64];
    __shared__ __align__(16) bf16 Bl[128 * 64];

    int tid = threadIdx.x, lane = tid & 63, w = tid >> 6;
    int quad = lane >> 4, lcol = lane & 15;
    int bx = blockIdx.x;
    int by = blockIdx.y;
    int wr = w >> 1, wc = w & 1;

    floatx4 z4 = {0.f, 0.f, 0.f, 0.f};
    floatx4 acc[4][4];
    for (int i = 0; i < 4; ++i)
        for (int j = 0; j < 4; ++j) acc[i][j] = z4;

    const bf16* Ag = X + (size_t)by * 128 * 1024;
    const bf16* Bg = W + (size_t)bx * 128 * 1024;

    for (int kt = 0; kt < 16; ++kt) {
        int k0 = kt * 64;
        __syncthreads();
#pragma unroll
        for (int j = 0; j < 4; ++j) {
            int c = (w * 4 + j) * 64 + lane;  // chunk 0..1023
            int row = c >> 3;                 // 0..127
            int dc = (c & 7) ^ (row & 7);
            gld16(Ag + (size_t)row * 1024 + k0 + dc * 8, &Al[(w * 4 + j) * 512]);
        }
#pragma unroll
        for (int j = 0; j < 4; ++j) {
            int c = (w * 4 + j) * 64 + lane;
            int row = c >> 3;
            int dc = (c & 7) ^ (row & 7);
            gld16(Bg + (size_t)row * 1024 + k0 + dc * 8, &Bl[(w * 4 + j) * 512]);
        }
        __syncthreads();

        bf16x8 bfr0[4], bfr1[4];
#pragma unroll
        for (int j = 0; j < 4; ++j) {
            int r = wc * 64 + j * 16 + lcol;
            bfr0[j] = *(const bf16x8*)&Bl[r * 64 + ((quad ^ (r & 7)) * 8)];
            bfr1[j] = *(const bf16x8*)&Bl[r * 64 + (((4 + quad) ^ (r & 7)) * 8)];
        }
#pragma unroll
        for (int i = 0; i < 4; ++i) {
            int r = wr * 64 + i * 16 + lcol;
            bf16x8 a0 = *(const bf16x8*)&Al[r * 64 + ((quad ^ (r & 7)) * 8)];
            bf16x8 a1 = *(const bf16x8*)&Al[r * 64 + (((4 + quad) ^ (r & 7)) * 8)];
#pragma unroll
            for (int j = 0; j < 4; ++j) {
                acc[i][j] = MFMA16(a0, bfr0[j], acc[i][j]);
                acc[i][j] = MFMA16(a1, bfr1[j], acc[i][j]);
            }
        }
    }

    int col0 = bx * 128 + wc * 64;
    int row0 = by * 128 + wr * 64;
    int seg = col0 >> 10;

    for (int i = 0; i < 4; ++i) {
        int m0 = row0 + i * 16 + quad * 4;
        int bb = m0 >> 10, n0 = m0 & 1023;
        for (int j = 0; j < 4; ++j) {
            int o = col0 + j * 16 + lcol;
            if (seg == 0) {
                int hh = o >> 6, d = o & 63;
                float qb = qbias[o];
                for (int r = 0; r < 4; ++r) {
                    // q scale 1/8 with log2e folded (softmax in log2 domain)
                    float v = (acc[i][j][r] + qb) * (0.125f * LOG2E);
                    qbuf[((size_t)((bb * 16 + hh) * 1024 + n0 + r)) * 64 + d] = (bf16)v;
                }
            } else if (seg == 1) {
                int o2 = o - 1024;
                int hh = o2 >> 6, d = o2 & 63;
                for (int r = 0; r < 4; ++r) {
                    kbuf[((size_t)((bb * 16 + hh) * 1024 + n0 + r)) * 64 + d] = (bf16)acc[i][j][r];
                }
            } else {
                int o2 = o - 2048;
                int hh = o2 >> 6, d = o2 & 63;
                float vbv = vbias[o2];
                bf16x4 pk;
                pk.x = (bf16)(acc[i][j][0] + vbv);
                pk.y = (bf16)(acc[i][j][1] + vbv);
                pk.z = (bf16)(acc[i][j][2] + vbv);
                pk.w = (bf16)(acc[i][j][3] + vbv);
                *(bf16x4*)&vbuf[((size_t)((bb * 16 + hh) * 64 + d)) * 1024 + n0] = pk;
            }
        }
    }
}

// ---------------- flash attention ----------------
// Block = (b, h, 64 q rows), 4 waves; wave owns ONE 16-row strip.
// S^T = MFMA(A=K permuted rows, B=Q, C=bias). The key permutation
//   key(j, m) = 32*(j>>1) + 8*(m>>2) + 4*(j&1) + (m&3)
// makes the C-layout output (lane quad, reg r) hold keys 8*quad+e directly,
// so (p[0][*], p[1][*]) packs straight into the O-MFMA B-fragment: no P LDS
// round-trip, no cross-lane ops. Mask via packed u64 bitmask select
// (masked key -> sv=0 -> p=1.0 == exp(1e-8) within bf16). O^T = MFMA(A=Vt,B=P).
// launch_bounds(256,5): 5 blocks/CU x 32KB = 160KB LDS exactly; VGPR cap 102
// >> ~60 demand (measured 52 at cap 128) -> no spill, +25% resident waves.
__global__ __launch_bounds__(256, 5) void flash_attn(
    const bf16* __restrict__ qbuf, const bf16* __restrict__ kbuf,
    const bf16* __restrict__ vbuf, const bf16* __restrict__ bias,
    const unsigned long long* __restrict__ om64, float* __restrict__ out) {
    __shared__ __align__(16) bf16 Kl[2][64 * 64];
    __shared__ __align__(16) bf16 Vl[2][64 * 64];

    int tid = threadIdx.x, lane = tid & 63, w = tid >> 6;
    int quad = lane >> 4, lcol = lane & 15;
    int bx = blockIdx.x;
    // XCD-aware decode (XCD = bx % 8): each XCD owns 2 heads x 16 q-tiles;
    // the 8 batch-blocks of a (h,q4) run back-to-back (bias tile 128KB x8
    // L2 reuse); K/V of (b,h) reused across the 16 q4 of that h (~2MB set).
    int xcd = bx & 7, slot = bx >> 3;
    int pair = xcd * 32 + (slot >> 3);  // 0..255
    int b = slot & 7;
    int h = pair >> 4, q4 = pair & 15;

    const bf16* kb = kbuf + ((size_t)((b * 16 + h) * 1024)) * 64;
    const bf16* vb = vbuf + ((size_t)((b * 16 + h) * 64)) * 1024;  // [d][n]
    const unsigned long long* mp = om64 + b * 16;

    int qrow = q4 * 64 + w * 16;
    const bf16* qp = qbuf + ((size_t)((b * 16 + h) * 1024 + qrow + lcol)) * 64;
    bf16x8 qf0 = *(const bf16x8*)(qp + quad * 8);
    bf16x8 qf1 = *(const bf16x8*)(qp + 32 + quad * 8);
    const bf16* bb = bias + (size_t)h * 1024 * 1024 + (size_t)(qrow + lcol) * 1024;

    floatx4 z4 = {0.f, 0.f, 0.f, 0.f};
    floatx4 oacc[4] = {z4, z4, z4, z4};
    float lrun = 0.f;

    // stage tile 0 into buffer 0
#pragma unroll
    for (int j = 0; j < 2; ++j) {
        int c = (w * 2 + j) * 64 + lane;
        int key = c >> 3;
        int dc = (c & 7) ^ GK(key);
        gld16(kb + (size_t)key * 64 + dc * 8, &Kl[0][(w * 2 + j) * 512]);
    }
#pragma unroll
    for (int j = 0; j < 2; ++j) {
        int c = (w * 2 + j) * 64 + lane;
        int d = c >> 3;
        int kc = (c & 7) ^ (d & 7);
        gld16(vb + (size_t)d * 1024 + kc * 8, &Vl[0][(w * 2 + j) * 512]);
    }

    // prefetch bias (bf16, PERMUTED key order matching S-MFMA C layout) + mask
    bf16x4 bf_[4];
#pragma unroll
    for (int j = 0; j < 4; ++j) {
        int kboff = ((j >> 1) << 5) + (quad << 3) + ((j & 1) << 2);
        bf_[j] = *(const bf16x4*)(bb + kboff);
    }
    unsigned long long mcur = mp[0];

    for (int kt = 0; kt < 16; ++kt) {
        int k0 = kt * 64;
        int cur = kt & 1, nxt = cur ^ 1;
        __syncthreads();  // buf[cur] staged; buf[nxt] free

        // stage tile kt+1 into buf[nxt]
        if (kt < 15) {
            int k1 = k0 + 64;
#pragma unroll
            for (int j = 0; j < 2; ++j) {
                int c = (w * 2 + j) * 64 + lane;
                int key = c >> 3;
                int dc = (c & 7) ^ GK(key);
                gld16(kb + (size_t)(k1 + key) * 64 + dc * 8, &Kl[nxt][(w * 2 + j) * 512]);
            }
#pragma unroll
            for (int j = 0; j < 2; ++j) {
                int c = (w * 2 + j) * 64 + lane;
                int d = c >> 3;
                int kc = (c & 7) ^ (d & 7);
                gld16(vb + (size_t)d * 1024 + k1 + kc * 8, &Vl[nxt][(w * 2 + j) * 512]);
            }
        }
        int kp = (kt < 15) ? k0 + 64 : 0;
        bf16x4 bn[4];
#pragma unroll
        for (int j = 0; j < 4; ++j) {
            int kboff = ((j >> 1) << 5) + (quad << 3) + ((j & 1) << 2);
            bn[j] = *(const bf16x4*)(bb + kp + kboff);
        }
        unsigned long long mn = mp[(kt < 15) ? kt + 1 : 0];

        // S^T + bias = MFMA(A=K permuted, B=Q, C=bias)
        floatx4 sacc[4];
#pragma unroll
        for (int j = 0; j < 4; ++j) {
            int key = ((j >> 1) << 5) + ((lcol >> 2) << 3) + ((j & 1) << 2) + (lcol & 3);
            int gk = GK(key);
            bf16x8 kf0 = *(const bf16x8*)&Kl[cur][key * 64 + ((quad ^ gk) * 8)];
            bf16x8 kf1 = *(const bf16x8*)&Kl[cur][key * 64 + (((4 + quad) ^ gk) * 8)];
            floatx4 binit;
            binit[0] = (float)bf_[j][0]; binit[1] = (float)bf_[j][1];
            binit[2] = (float)bf_[j][2]; binit[3] = (float)bf_[j][3];
            sacc[j] = MFMA16(kf0, qf0, binit);
            sacc[j] = MFMA16(kf1, qf1, sacc[j]);
        }

        // mask-select + p = exp2(sv); per-lane lrun partials (no shuffles).
        // this lane's 16 keys are bits {8q..8q+7, 32+8q..32+8q+7} of mcur,
        // packed so element (j,r) is bit j*4+r of mbits.
        unsigned int mbits = ((unsigned int)(mcur >> (8 * quad)) & 0xffu) |
                             (((unsigned int)(mcur >> (32 + 8 * quad)) & 0xffu) << 8);
        float p[4][4];
#pragma unroll
        for (int j = 0; j < 4; ++j)
#pragma unroll
            for (int r = 0; r < 4; ++r) {
                float sv = ((mbits >> (j * 4 + r)) & 1u) ? sacc[j][r] : 0.f;
                p[j][r] = __builtin_amdgcn_exp2f(sv);
            }
        // tree-reduce psum: 4-level dependency instead of a 16-add serial chain
        float ps0 = (p[0][0] + p[0][1]) + (p[0][2] + p[0][3]);
        float ps1 = (p[1][0] + p[1][1]) + (p[1][2] + p[1][3]);
        float ps2 = (p[2][0] + p[2][1]) + (p[2][2] + p[2][3]);
        float ps3 = (p[3][0] + p[3][1]) + (p[3][2] + p[3][3]);
        lrun += (ps0 + ps1) + (ps2 + ps3);

        // pack P straight into B-operand fragments (keys already lane-local):
        // pf0 = keys 8q+0..7 = (p[0][0..3], p[1][0..3]); pf1 = +32.
        bf16x8 pf0, pf1;
        pf0[0] = (bf16)p[0][0]; pf0[1] = (bf16)p[0][1];
        pf0[2] = (bf16)p[0][2]; pf0[3] = (bf16)p[0][3];
        pf0[4] = (bf16)p[1][0]; pf0[5] = (bf16)p[1][1];
        pf0[6] = (bf16)p[1][2]; pf0[7] = (bf16)p[1][3];
        pf1[0] = (bf16)p[2][0]; pf1[1] = (bf16)p[2][1];
        pf1[2] = (bf16)p[2][2]; pf1[3] = (bf16)p[2][3];
        pf1[4] = (bf16)p[3][0]; pf1[5] = (bf16)p[3][1];
        pf1[6] = (bf16)p[3][2]; pf1[7] = (bf16)p[3][3];

        // O^T += Vt P^T
#pragma unroll
        for (int jd = 0; jd < 4; ++jd) {
            int dd = jd * 16 + lcol;
            bf16x8 vf0 = *(const bf16x8*)&Vl[cur][dd * 64 + ((quad ^ (dd & 7)) * 8)];
            bf16x8 vf1 = *(const bf16x8*)&Vl[cur][dd * 64 + (((4 + quad) ^ (dd & 7)) * 8)];
            oacc[jd] = MFMA16(vf0, pf0, oacc[jd]);
            oacc[jd] = MFMA16(vf1, pf1, oacc[jd]);
        }

        // rotate bias/mask prefetch
#pragma unroll
        for (int j = 0; j < 4; ++j) bf_[j] = bn[j];
        mcur = mn;
    }

    // epilogue: reduce lrun across quads (once), normalize, store
    float l = lrun;
    l += __shfl_xor(l, 16);
    l += __shfl_xor(l, 32);
    float linv = 1.f / l;
#pragma unroll
    for (int jd = 0; jd < 4; ++jd) {
        float4 st;
        st.x = oacc[jd][0] * linv;
        st.y = oacc[jd][1] * linv;
        st.z = oacc[jd][2] * linv;
        st.w = oacc[jd][3] * linv;
        *(float4*)&out[((size_t)(b * 1024 + qrow + lcol)) * 1024 + h * 64 + jd * 16 + quad * 4] = st;
    }
}

// ---------------- launch ----------------
extern "C" void kernel_launch(void* const* d_in, const int* in_sizes, int n_in,
                              void* d_out, int out_size, void* d_ws, size_t ws_size,
                              hipStream_t stream) {
    const float* hs   = (const float*)d_in[0];
    const float* qkvw = (const float*)d_in[1];
    const float* qb   = (const float*)d_in[2];
    const float* vbi  = (const float*)d_in[3];
    const float* rel  = (const float*)d_in[4];
    const float* rel2 = (const float*)d_in[5];
    const int*   msk  = (const int*)d_in[6];
    float* out = (float*)d_out;

    char* w = (char*)d_ws;
    bf16* Xb = (bf16*)w;  w += (size_t)8388608 * 2;
    bf16* Wb = (bf16*)w;  w += (size_t)3145728 * 2;
    bf16* Bb = (bf16*)w;  w += (size_t)16777216 * 2;
    bf16* Qb = (bf16*)w;  w += (size_t)8388608 * 2;
    bf16* Kb = (bf16*)w;  w += (size_t)8388608 * 2;
    bf16* Vb = (bf16*)w;  w += (size_t)8388608 * 2;
    unsigned long long* OM = (unsigned long long*)w; w += (size_t)128 * 8;

    prep_kernel<<<27680, 256, 0, stream>>>(hs, qkvw, rel, rel2, msk, Xb, Wb, Bb, OM);
    qkv_gemm<<<dim3(24, 64), 256, 0, stream>>>(Xb, Wb, qb, vbi, Qb, Kb, Vb);
    flash_attn<<<2048, 256, 0, stream>>>(Qb, Kb, Vb, Bb, OM, out);
}

// Round 9
// 318.111 us; speedup vs baseline: 1.2171x; 1.0599x over previous
//
#include <hip/hip_runtime.h>

// LayoutLMv2 self-attention, MI355X.  B=8 N=1024 H=16 D=64.
// Fused prep (fp32->bf16 converts, bias combine w/ log2e fold, mask->u64
// bitmasks) in ONE dispatch; bf16 MFMA QKV GEMM (128x128 tile, BK=64, 16
// K-steps, zero-conflict 64-wide swizzle, launch_bounds(256,4) VGPR cap);
// flash attention: 1 q-strip/wave, MAX-FREE log2-domain softmax, precombined
// bf16 bias folded into MFMA C-operand, ZERO LDS round-trip for P
// (permuted-key S-MFMA output IS the O-MFMA B-fragment), packed-bitmask
// masking, tree-reduced psum, s_setprio around MFMA clusters (T5: waves of
// different blocks are desynced on a SIMD -> scheduler favors MFMA wave).
// launch_bounds(256,4): r8 showed 5 blocks/CU (160KB LDS exactly) causes
// L2 thrash + scratch traffic (WRITE_SIZE +15MB) -> keep 4 blocks/CU.

typedef __bf16 bf16;
typedef __bf16 bf16x8 __attribute__((ext_vector_type(8)));
typedef __bf16 bf16x4 __attribute__((ext_vector_type(4)));
typedef float floatx4 __attribute__((ext_vector_type(4)));

#define MFMA16(a, b, c) __builtin_amdgcn_mfma_f32_16x16x32_bf16((a), (b), (c), 0, 0, 0)

#define LOG2E 1.4426950408889634f

// K-tile LDS chunk swizzle for flash: g bits = (b0^b3, b1^b4, b2^b3) of the
// 6-bit key; spreads the PERMUTED S-MFMA fragment reads over all 8 16B groups.
#define GK(key) ((((key) ^ ((key) >> 3)) & 3) | (((((key) >> 2) ^ ((key) >> 3)) & 1) << 2))

__device__ __forceinline__ void gld16(const bf16* g, bf16* l) {
    __builtin_amdgcn_global_load_lds(
        (const __attribute__((address_space(1))) unsigned int*)g,
        (__attribute__((address_space(3))) unsigned int*)l, 16, 0, 0);
}

// ---------------- fused prep kernel ----------------
// blocks [0,16384): bias combine (rel+rel2)*log2e -> bf16
// blocks [16384,24576): cvt hidden_states f32->bf16
// blocks [24576,27648): cvt qkv_w f32->bf16
// blocks [27648,27680): mask -> packed u64 keep-bitmasks
__global__ __launch_bounds__(256) void prep_kernel(
    const float* __restrict__ hs, const float* __restrict__ qkvw,
    const float* __restrict__ rel, const float* __restrict__ rel2,
    const int* __restrict__ msk,
    bf16* __restrict__ Xb, bf16* __restrict__ Wb, bf16* __restrict__ Bb,
    unsigned long long* __restrict__ OM) {
    int bid = blockIdx.x, t = threadIdx.x;
    if (bid < 16384) {
        int i = bid * 256 + t;
        float4 va = ((const float4*)rel)[i];
        float4 vb = ((const float4*)rel2)[i];
        bf16x4 o;
        o.x = (bf16)((va.x + vb.x) * LOG2E); o.y = (bf16)((va.y + vb.y) * LOG2E);
        o.z = (bf16)((va.z + vb.z) * LOG2E); o.w = (bf16)((va.w + vb.w) * LOG2E);
        ((bf16x4*)Bb)[i] = o;
    } else if (bid < 24576) {
        int i = (bid - 16384) * 256 + t;
        float4 v = ((const float4*)hs)[i];
        bf16x4 o;
        o.x = (bf16)v.x; o.y = (bf16)v.y; o.z = (bf16)v.z; o.w = (bf16)v.w;
        ((bf16x4*)Xb)[i] = o;
    } else if (bid < 27648) {
        int i = (bid - 24576) * 256 + t;
        float4 v = ((const float4*)qkvw)[i];
        bf16x4 o;
        o.x = (bf16)v.x; o.y = (bf16)v.y; o.z = (bf16)v.z; o.w = (bf16)v.w;
        ((bf16x4*)Wb)[i] = o;
    } else {
        int tid = (bid - 27648) * 256 + t;
        int gw = tid >> 6, lane = tid & 63;  // gw = b*16 + tile, 0..127
        bool keep = (msk[gw * 64 + lane] == 0);
        unsigned long long bal = __ballot(keep);
        if (lane == 0) OM[gw] = bal;
    }
}

// ---------------- QKV GEMM ----------------
// 128x128 tile, BK=64, single-buffered LDS (32KB), 2 barriers per K-step but
// only 16 K-steps and 32 MFMA/step.  64-wide staging/fragment swizzle
// (measured SQ_LDS_BANK_CONFLICT = 0).  launch_bounds(256,4) caps VGPR at 128
// so 4 blocks/CU are guaranteed.
__global__ __launch_bounds__(256, 4) void qkv_gemm(
    const bf16* __restrict__ X, const bf16* __restrict__ W,
    const float* __restrict__ qbias, const float* __restrict__ vbias,
    bf16* __restrict__ qbuf, bf16* __restrict__ kbuf, bf16* __restrict__ vbuf) {
    __shared__ __align__(16) bf16 Al[128 * 64];
    __shared__ __align__(16) bf16 Bl[128 * 64];

    int tid = threadIdx.x, lane = tid & 63, w = tid >> 6;
    int quad = lane >> 4, lcol = lane & 15;
    int bx = blockIdx.x;
    int by = blockIdx.y;
    int wr = w >> 1, wc = w & 1;

    floatx4 z4 = {0.f, 0.f, 0.f, 0.f};
    floatx4 acc[4][4];
    for (int i = 0; i < 4; ++i)
        for (int j = 0; j < 4; ++j) acc[i][j] = z4;

    const bf16* Ag = X + (size_t)by * 128 * 1024;
    const bf16* Bg = W + (size_t)bx * 128 * 1024;

    for (int kt = 0; kt < 16; ++kt) {
        int k0 = kt * 64;
        __syncthreads();
#pragma unroll
        for (int j = 0; j < 4; ++j) {
            int c = (w * 4 + j) * 64 + lane;  // chunk 0..1023
            int row = c >> 3;                 // 0..127
            int dc = (c & 7) ^ (row & 7);
            gld16(Ag + (size_t)row * 1024 + k0 + dc * 8, &Al[(w * 4 + j) * 512]);
        }
#pragma unroll
        for (int j = 0; j < 4; ++j) {
            int c = (w * 4 + j) * 64 + lane;
            int row = c >> 3;
            int dc = (c & 7) ^ (row & 7);
            gld16(Bg + (size_t)row * 1024 + k0 + dc * 8, &Bl[(w * 4 + j) * 512]);
        }
        __syncthreads();

        bf16x8 bfr0[4], bfr1[4];
#pragma unroll
        for (int j = 0; j < 4; ++j) {
            int r = wc * 64 + j * 16 + lcol;
            bfr0[j] = *(const bf16x8*)&Bl[r * 64 + ((quad ^ (r & 7)) * 8)];
            bfr1[j] = *(const bf16x8*)&Bl[r * 64 + (((4 + quad) ^ (r & 7)) * 8)];
        }
        __builtin_amdgcn_s_setprio(1);
#pragma unroll
        for (int i = 0; i < 4; ++i) {
            int r = wr * 64 + i * 16 + lcol;
            bf16x8 a0 = *(const bf16x8*)&Al[r * 64 + ((quad ^ (r & 7)) * 8)];
            bf16x8 a1 = *(const bf16x8*)&Al[r * 64 + (((4 + quad) ^ (r & 7)) * 8)];
#pragma unroll
            for (int j = 0; j < 4; ++j) {
                acc[i][j] = MFMA16(a0, bfr0[j], acc[i][j]);
                acc[i][j] = MFMA16(a1, bfr1[j], acc[i][j]);
            }
        }
        __builtin_amdgcn_s_setprio(0);
    }

    int col0 = bx * 128 + wc * 64;
    int row0 = by * 128 + wr * 64;
    int seg = col0 >> 10;

    for (int i = 0; i < 4; ++i) {
        int m0 = row0 + i * 16 + quad * 4;
        int bb = m0 >> 10, n0 = m0 & 1023;
        for (int j = 0; j < 4; ++j) {
            int o = col0 + j * 16 + lcol;
            if (seg == 0) {
                int hh = o >> 6, d = o & 63;
                float qb = qbias[o];
                for (int r = 0; r < 4; ++r) {
                    // q scale 1/8 with log2e folded (softmax in log2 domain)
                    float v = (acc[i][j][r] + qb) * (0.125f * LOG2E);
                    qbuf[((size_t)((bb * 16 + hh) * 1024 + n0 + r)) * 64 + d] = (bf16)v;
                }
            } else if (seg == 1) {
                int o2 = o - 1024;
                int hh = o2 >> 6, d = o2 & 63;
                for (int r = 0; r < 4; ++r) {
                    kbuf[((size_t)((bb * 16 + hh) * 1024 + n0 + r)) * 64 + d] = (bf16)acc[i][j][r];
                }
            } else {
                int o2 = o - 2048;
                int hh = o2 >> 6, d = o2 & 63;
                float vbv = vbias[o2];
                bf16x4 pk;
                pk.x = (bf16)(acc[i][j][0] + vbv);
                pk.y = (bf16)(acc[i][j][1] + vbv);
                pk.z = (bf16)(acc[i][j][2] + vbv);
                pk.w = (bf16)(acc[i][j][3] + vbv);
                *(bf16x4*)&vbuf[((size_t)((bb * 16 + hh) * 64 + d)) * 1024 + n0] = pk;
            }
        }
    }
}

// ---------------- flash attention ----------------
// Block = (b, h, 64 q rows), 4 waves; wave owns ONE 16-row strip.
// S^T = MFMA(A=K permuted rows, B=Q, C=bias). The key permutation
//   key(j, m) = 32*(j>>1) + 8*(m>>2) + 4*(j&1) + (m&3)
// makes the C-layout output (lane quad, reg r) hold keys 8*quad+e directly,
// so (p[0][*], p[1][*]) packs straight into the O-MFMA B-fragment: no P LDS
// round-trip, no cross-lane ops. Mask via packed u64 bitmask select
// (masked key -> sv=0 -> p=1.0 == exp(1e-8) within bf16). O^T = MFMA(A=Vt,B=P).
// launch_bounds(256,4): r8 proved (256,5) regresses (L2 thrash + scratch).
__global__ __launch_bounds__(256, 4) void flash_attn(
    const bf16* __restrict__ qbuf, const bf16* __restrict__ kbuf,
    const bf16* __restrict__ vbuf, const bf16* __restrict__ bias,
    const unsigned long long* __restrict__ om64, float* __restrict__ out) {
    __shared__ __align__(16) bf16 Kl[2][64 * 64];
    __shared__ __align__(16) bf16 Vl[2][64 * 64];

    int tid = threadIdx.x, lane = tid & 63, w = tid >> 6;
    int quad = lane >> 4, lcol = lane & 15;
    int bx = blockIdx.x;
    // XCD-aware decode (XCD = bx % 8): each XCD owns 2 heads x 16 q-tiles;
    // the 8 batch-blocks of a (h,q4) run back-to-back (bias tile 128KB x8
    // L2 reuse); K/V of (b,h) reused across the 16 q4 of that h (~2MB set).
    int xcd = bx & 7, slot = bx >> 3;
    int pair = xcd * 32 + (slot >> 3);  // 0..255
    int b = slot & 7;
    int h = pair >> 4, q4 = pair & 15;

    const bf16* kb = kbuf + ((size_t)((b * 16 + h) * 1024)) * 64;
    const bf16* vb = vbuf + ((size_t)((b * 16 + h) * 64)) * 1024;  // [d][n]
    const unsigned long long* mp = om64 + b * 16;

    int qrow = q4 * 64 + w * 16;
    const bf16* qp = qbuf + ((size_t)((b * 16 + h) * 1024 + qrow + lcol)) * 64;
    bf16x8 qf0 = *(const bf16x8*)(qp + quad * 8);
    bf16x8 qf1 = *(const bf16x8*)(qp + 32 + quad * 8);
    const bf16* bb = bias + (size_t)h * 1024 * 1024 + (size_t)(qrow + lcol) * 1024;

    floatx4 z4 = {0.f, 0.f, 0.f, 0.f};
    floatx4 oacc[4] = {z4, z4, z4, z4};
    float lrun = 0.f;

    // stage tile 0 into buffer 0
#pragma unroll
    for (int j = 0; j < 2; ++j) {
        int c = (w * 2 + j) * 64 + lane;
        int key = c >> 3;
        int dc = (c & 7) ^ GK(key);
        gld16(kb + (size_t)key * 64 + dc * 8, &Kl[0][(w * 2 + j) * 512]);
    }
#pragma unroll
    for (int j = 0; j < 2; ++j) {
        int c = (w * 2 + j) * 64 + lane;
        int d = c >> 3;
        int kc = (c & 7) ^ (d & 7);
        gld16(vb + (size_t)d * 1024 + kc * 8, &Vl[0][(w * 2 + j) * 512]);
    }

    // prefetch bias (bf16, PERMUTED key order matching S-MFMA C layout) + mask
    bf16x4 bf_[4];
#pragma unroll
    for (int j = 0; j < 4; ++j) {
        int kboff = ((j >> 1) << 5) + (quad << 3) + ((j & 1) << 2);
        bf_[j] = *(const bf16x4*)(bb + kboff);
    }
    unsigned long long mcur = mp[0];

    for (int kt = 0; kt < 16; ++kt) {
        int k0 = kt * 64;
        int cur = kt & 1, nxt = cur ^ 1;
        __syncthreads();  // buf[cur] staged; buf[nxt] free

        // stage tile kt+1 into buf[nxt]
        if (kt < 15) {
            int k1 = k0 + 64;
#pragma unroll
            for (int j = 0; j < 2; ++j) {
                int c = (w * 2 + j) * 64 + lane;
                int key = c >> 3;
                int dc = (c & 7) ^ GK(key);
                gld16(kb + (size_t)(k1 + key) * 64 + dc * 8, &Kl[nxt][(w * 2 + j) * 512]);
            }
#pragma unroll
            for (int j = 0; j < 2; ++j) {
                int c = (w * 2 + j) * 64 + lane;
                int d = c >> 3;
                int kc = (c & 7) ^ (d & 7);
                gld16(vb + (size_t)d * 1024 + k1 + kc * 8, &Vl[nxt][(w * 2 + j) * 512]);
            }
        }
        int kp = (kt < 15) ? k0 + 64 : 0;
        bf16x4 bn[4];
#pragma unroll
        for (int j = 0; j < 4; ++j) {
            int kboff = ((j >> 1) << 5) + (quad << 3) + ((j & 1) << 2);
            bn[j] = *(const bf16x4*)(bb + kp + kboff);
        }
        unsigned long long mn = mp[(kt < 15) ? kt + 1 : 0];

        // S^T + bias = MFMA(A=K permuted, B=Q, C=bias)
        floatx4 sacc[4];
        __builtin_amdgcn_s_setprio(1);
#pragma unroll
        for (int j = 0; j < 4; ++j) {
            int key = ((j >> 1) << 5) + ((lcol >> 2) << 3) + ((j & 1) << 2) + (lcol & 3);
            int gk = GK(key);
            bf16x8 kf0 = *(const bf16x8*)&Kl[cur][key * 64 + ((quad ^ gk) * 8)];
            bf16x8 kf1 = *(const bf16x8*)&Kl[cur][key * 64 + (((4 + quad) ^ gk) * 8)];
            floatx4 binit;
            binit[0] = (float)bf_[j][0]; binit[1] = (float)bf_[j][1];
            binit[2] = (float)bf_[j][2]; binit[3] = (float)bf_[j][3];
            sacc[j] = MFMA16(kf0, qf0, binit);
            sacc[j] = MFMA16(kf1, qf1, sacc[j]);
        }
        __builtin_amdgcn_s_setprio(0);

        // mask-select + p = exp2(sv); per-lane lrun partials (no shuffles).
        // this lane's 16 keys are bits {8q..8q+7, 32+8q..32+8q+7} of mcur,
        // packed so element (j,r) is bit j*4+r of mbits.
        unsigned int mbits = ((unsigned int)(mcur >> (8 * quad)) & 0xffu) |
                             (((unsigned int)(mcur >> (32 + 8 * quad)) & 0xffu) << 8);
        float p[4][4];
#pragma unroll
        for (int j = 0; j < 4; ++j)
#pragma unroll
            for (int r = 0; r < 4; ++r) {
                float sv = ((mbits >> (j * 4 + r)) & 1u) ? sacc[j][r] : 0.f;
                p[j][r] = __builtin_amdgcn_exp2f(sv);
            }
        // tree-reduce psum: 4-level dependency instead of a 16-add serial chain
        float ps0 = (p[0][0] + p[0][1]) + (p[0][2] + p[0][3]);
        float ps1 = (p[1][0] + p[1][1]) + (p[1][2] + p[1][3]);
        float ps2 = (p[2][0] + p[2][1]) + (p[2][2] + p[2][3]);
        float ps3 = (p[3][0] + p[3][1]) + (p[3][2] + p[3][3]);
        lrun += (ps0 + ps1) + (ps2 + ps3);

        // pack P straight into B-operand fragments (keys already lane-local):
        // pf0 = keys 8q+0..7 = (p[0][0..3], p[1][0..3]); pf1 = +32.
        bf16x8 pf0, pf1;
        pf0[0] = (bf16)p[0][0]; pf0[1] = (bf16)p[0][1];
        pf0[2] = (bf16)p[0][2]; pf0[3] = (bf16)p[0][3];
        pf0[4] = (bf16)p[1][0]; pf0[5] = (bf16)p[1][1];
        pf0[6] = (bf16)p[1][2]; pf0[7] = (bf16)p[1][3];
        pf1[0] = (bf16)p[2][0]; pf1[1] = (bf16)p[2][1];
        pf1[2] = (bf16)p[2][2]; pf1[3] = (bf16)p[2][3];
        pf1[4] = (bf16)p[3][0]; pf1[5] = (bf16)p[3][1];
        pf1[6] = (bf16)p[3][2]; pf1[7] = (bf16)p[3][3];

        // O^T += Vt P^T
        __builtin_amdgcn_s_setprio(1);
#pragma unroll
        for (int jd = 0; jd < 4; ++jd) {
            int dd = jd * 16 + lcol;
            bf16x8 vf0 = *(const bf16x8*)&Vl[cur][dd * 64 + ((quad ^ (dd & 7)) * 8)];
            bf16x8 vf1 = *(const bf16x8*)&Vl[cur][dd * 64 + (((4 + quad) ^ (dd & 7)) * 8)];
            oacc[jd] = MFMA16(vf0, pf0, oacc[jd]);
            oacc[jd] = MFMA16(vf1, pf1, oacc[jd]);
        }
        __builtin_amdgcn_s_setprio(0);

        // rotate bias/mask prefetch
#pragma unroll
        for (int j = 0; j < 4; ++j) bf_[j] = bn[j];
        mcur = mn;
    }

    // epilogue: reduce lrun across quads (once), normalize, store
    float l = lrun;
    l += __shfl_xor(l, 16);
    l += __shfl_xor(l, 32);
    float linv = 1.f / l;
#pragma unroll
    for (int jd = 0; jd < 4; ++jd) {
        float4 st;
        st.x = oacc[jd][0] * linv;
        st.y = oacc[jd][1] * linv;
        st.z = oacc[jd][2] * linv;
        st.w = oacc[jd][3] * linv;
        *(float4*)&out[((size_t)(b * 1024 + qrow + lcol)) * 1024 + h * 64 + jd * 16 + quad * 4] = st;
    }
}

// ---------------- launch ----------------
extern "C" void kernel_launch(void* const* d_in, const int* in_sizes, int n_in,
                              void* d_out, int out_size, void* d_ws, size_t ws_size,
                              hipStream_t stream) {
    const float* hs   = (const float*)d_in[0];
    const float* qkvw = (const float*)d_in[1];
    const float* qb   = (const float*)d_in[2];
    const float* vbi  = (const float*)d_in[3];
    const float* rel  = (const float*)d_in[4];
    const float* rel2 = (const float*)d_in[5];
    const int*   msk  = (const int*)d_in[6];
    float* out = (float*)d_out;

    char* w = (char*)d_ws;
    bf16* Xb = (bf16*)w;  w += (size_t)8388608 * 2;
    bf16* Wb = (bf16*)w;  w += (size_t)3145728 * 2;
    bf16* Bb = (bf16*)w;  w += (size_t)16777216 * 2;
    bf16* Qb = (bf16*)w;  w += (size_t)8388608 * 2;
    bf16* Kb = (bf16*)w;  w += (size_t)8388608 * 2;
    bf16* Vb = (bf16*)w;  w += (size_t)8388608 * 2;
    unsigned long long* OM = (unsigned long long*)w; w += (size_t)128 * 8;

    prep_kernel<<<27680, 256, 0, stream>>>(hs, qkvw, rel, rel2, msk, Xb, Wb, Bb, OM);
    qkv_gemm<<<dim3(24, 64), 256, 0, stream>>>(Xb, Wb, qb, vbi, Qb, Kb, Vb);
    flash_attn<<<2048, 256, 0, stream>>>(Qb, Kb, Vb, Bb, OM, out);
}